// Round 3
// baseline (230.815 us; speedup 1.0000x reference)
//
#include <hip/hip_runtime.h>

// KANConv2D: out[b,h,w,f] = conv3x3(x,K)[.,f] + exp(-gamma * d[.,f]) + bias[f]
// d = ||patch||^2 + ||c_f||^2 - 2*patch.c_f ; gamma = (N*F)/(2*sum(d))
//
// v3: 3 launches. k_main stages a persistent zero-padded bf16 image tile
//     (4 rows x 66 px x 64 ch) once per block; all 9 (ki,kj) A-views are LDS
//     offsets. Per-kc only B is staged (register-prefetched from L2).
//     ||patch||^2 computed in-block from the LDS tile (s + 3x3 box sum).
//     conv(fp16)+d(fp16) packed into d_out; in-place finalize.

#define B_ 32
#define H_ 64
#define W_ 64
#define C_ 64
#define F_ 128
#define P_ 576
#define NPIX (B_*H_*W_)          // 131072
#define NF   (NPIX*F_)           // 16777216

typedef __bf16  bf16x8 __attribute__((ext_vector_type(8)));
typedef float   f32x4  __attribute__((ext_vector_type(4)));

union HU { _Float16 h; ushort u; };
union FU { float f; uint u; };

__device__ __forceinline__ ushort f2bf(float f) {
    FU v; v.f = f;
    return (ushort)((v.u + 0x7fffu + ((v.u >> 16) & 1u)) >> 16);   // RNE
}
__device__ __forceinline__ uint pk(float a, float b) {
    return (uint)f2bf(a) | ((uint)f2bf(b) << 16);
}
__device__ __forceinline__ ushort f2h(float f) { HU h; h.h = (_Float16)f; return h.u; }
__device__ __forceinline__ float  h2f(ushort u) { HU h; h.u = u; return (float)h.h; }
__device__ __forceinline__ float  bflo(uint u) { FU v; v.u = u << 16; return v.f; }
__device__ __forceinline__ float  bfhi(uint u) { FU v; v.u = u & 0xffff0000u; return v.f; }

// ---------------- P: transpose+convert B mats (blocks 0..287), cn+accum (block 288)
__global__ void k_prep(const float* __restrict__ wgt, const float* __restrict__ ctrl,
                       ushort* __restrict__ Btw, ushort* __restrict__ Btc,
                       float* __restrict__ cn, float* __restrict__ accum) {
    if (blockIdx.x < 288) {
        int e = blockIdx.x * 256 + threadIdx.x;   // < 73728
        int p = e >> 7, f = e & 127;
        Btw[f * P_ + p] = f2bf(wgt[e]);
        Btc[f * P_ + p] = f2bf(ctrl[e]);
    } else if (threadIdx.x < 128) {
        int f = threadIdx.x;
        float s = 0.f;
        for (int p = 0; p < P_; ++p) { float v = ctrl[p * F_ + f]; s += v * v; }
        cn[f] = s;
        if (f == 0) accum[0] = 0.f;
    }
}

// ---------------- D: fused dual implicit GEMM ----------------
// 512 threads = 8 waves; tile = 128 rows (2 image rows) x 128 F.
// waves 0-3: conv (32 rows each), waves 4-7: dot (32 rows each).
// LDS: lI [4][68][64] bf16 image tile (XOR-swizzled 16B chunks, zero-padded),
//      lB [2][128][64] bf16 (swizzled), sArr [4][68] f32, pnArr [128] f32.
__launch_bounds__(512, 4)
__global__ void k_main(const float* __restrict__ in,
                       const ushort* __restrict__ Btw, const ushort* __restrict__ Btc,
                       const float* __restrict__ bias, const float* __restrict__ cn,
                       uint* __restrict__ out, float* __restrict__ accum) {
    __shared__ __attribute__((aligned(16))) ushort smem[34592];   // 69184 B
    ushort* lI   = smem;                       // 17408 ush
    ushort* lB   = smem + 17408;               // 16384 ush
    float*  sArr = (float*)(smem + 33792);     // 272 f32 (stride 68)
    float*  pnAr = (float*)(smem + 33792 + 544);  // 128 f32

    const int tid = threadIdx.x;
    const int n0  = blockIdx.x * 128;          // 2 image rows, same image
    const int b   = n0 >> 12;
    const int y0  = (n0 >> 6) & 63;
    const float* inb = in + b * 262144;

    const int w     = tid >> 6, lane = tid & 63;
    const int mat   = w >> 2;                  // 0: conv, 1: dot
    const int mrow0 = (w & 3) * 32;
    const int quad  = lane >> 4, l16 = lane & 15;

    // B staging addressing (per thread, fixed across kc)
    const ushort* bsrc[4]; int bdst[4];
    #pragma unroll
    for (int i = 0; i < 4; ++i) {
        int idx = tid + i * 512;
        int m2 = idx >> 10, f = (idx >> 3) & 127, cc = idx & 7;
        bsrc[i] = (m2 ? Btc : Btw) + f * P_ + cc * 8;
        bdst[i] = m2 * 8192 + f * 64 + ((cc ^ (f & 7)) << 3);
    }
    uint4 pb[4];
    #pragma unroll
    for (int i = 0; i < 4; ++i) pb[i] = *(const uint4*)bsrc[i];   // kc=0 prefetch

    // ---- stage image tile once: 4 rows x 68 px x 8 chunks = 2176 chunks
    #pragma unroll
    for (int p = 0; p < 5; ++p) {
        int g = tid + p * 512;
        if (g < 2176) {
            int row4 = g / 544;                // 544 = 68*8
            int rem  = g - row4 * 544;
            int px = rem >> 3, c = rem & 7;
            int y = y0 + row4 - 1, x = px - 1;
            float4 v0 = make_float4(0.f, 0.f, 0.f, 0.f), v1 = v0;
            if (y >= 0 && y < 64 && x >= 0 && x < 64) {
                const float* sp = inb + y * 4096 + x * 64 + c * 8;
                v0 = *(const float4*)sp;
                v1 = *(const float4*)(sp + 4);
            }
            uint4 o = { pk(v0.x, v0.y), pk(v0.z, v0.w), pk(v1.x, v1.y), pk(v1.z, v1.w) };
            *(uint4*)&lI[(row4 * 68 + px) * 64 + ((c ^ (px & 7)) << 3)] = o;
        }
    }
    __syncthreads();

    // ---- s[row4][px] = channel sqnorm of tile pixel (zero pixels give 0)
    if (tid < 264) {
        int row4 = tid / 66, px = tid - row4 * 66;
        const ushort* base = &lI[(row4 * 68 + px) * 64];
        float s = 0.f;
        #pragma unroll
        for (int j = 0; j < 8; ++j) {
            int jj = (j + px) & 7;             // rotate to spread banks
            uint4 v = *(const uint4*)&base[jj << 3];
            float a0 = bflo(v.x), a1 = bfhi(v.x), a2 = bflo(v.y), a3 = bfhi(v.y);
            float a4 = bflo(v.z), a5 = bfhi(v.z), a6 = bflo(v.w), a7 = bfhi(v.w);
            s += a0*a0 + a1*a1 + a2*a2 + a3*a3 + a4*a4 + a5*a5 + a6*a6 + a7*a7;
        }
        sArr[row4 * 68 + px] = s;
    }
    __syncthreads();

    // ---- pn[r] = 3x3 box sum (zero-padding already in sArr)
    if (tid < 128) {
        int yr = tid >> 6, x = tid & 63;
        float a = 0.f;
        #pragma unroll
        for (int dr = 0; dr < 3; ++dr)
            #pragma unroll
            for (int dc = 0; dc < 3; ++dc)
                a += sArr[(yr + dr) * 68 + x + dc];
        pnAr[tid] = a;
    }
    // (pn consumed only after later barriers)

    f32x4 acc[2][8];
    #pragma unroll
    for (int mt = 0; mt < 2; ++mt)
        #pragma unroll
        for (int nt = 0; nt < 8; ++nt)
            acc[mt][nt] = (f32x4){0.f, 0.f, 0.f, 0.f};

    const int yrA = mrow0 >> 6;                // image row within tile (0/1)
    const int xbA = mrow0 & 63;                // 0 or 32

    for (int kc = 0; kc < 9; ++kc) {
        const int ki = kc / 3, kj = kc - 3 * ki;

        __syncthreads();                        // protect lB readers of kc-1
        #pragma unroll
        for (int i = 0; i < 4; ++i) *(uint4*)&lB[bdst[i]] = pb[i];
        if (kc < 8) {
            #pragma unroll
            for (int i = 0; i < 4; ++i)
                pb[i] = *(const uint4*)(bsrc[i] + (kc + 1) * 64);   // overlap w/ MFMA
        }
        __syncthreads();

        const int rbase = (yrA + ki) * 68;
        const int px0   = xbA + l16 + kj;       // a0 padded col
        const int px1   = px0 + 16;             // a1 padded col (same &7 key)
        const int ad0   = (rbase + px0) * 64;
        const int ad1   = (rbase + px1) * 64;
        const ushort* lBm = lB + mat * 8192;

        #pragma unroll
        for (int ks = 0; ks < 2; ++ks) {
            const int c  = ks * 4 + quad;
            bf16x8 a0 = *(const bf16x8*)&lI[ad0 + ((c ^ (px0 & 7)) << 3)];
            bf16x8 a1 = *(const bf16x8*)&lI[ad1 + ((c ^ (px0 & 7)) << 3)];
            const int sw = (c ^ (l16 & 7)) << 3;
            #pragma unroll
            for (int nt = 0; nt < 8; ++nt) {
                bf16x8 bq = *(const bf16x8*)&lBm[(nt * 16 + l16) * 64 + sw];
                acc[0][nt] = __builtin_amdgcn_mfma_f32_16x16x32_bf16(a0, bq, acc[0][nt], 0, 0, 0);
                acc[1][nt] = __builtin_amdgcn_mfma_f32_16x16x32_bf16(a1, bq, acc[1][nt], 0, 0, 0);
            }
        }
    }

    // ---- epilogue: C/D layout col=lane&15, row=quad*4+reg [m89/m91]
    // exchange region reuses lI (34816 B): slot per (wave&3, lane), stride 68 ush
    ushort* exch = smem;
    __syncthreads();
    if (mat == 1) {
        float pv[2][4];
        #pragma unroll
        for (int mt = 0; mt < 2; ++mt)
            #pragma unroll
            for (int r = 0; r < 4; ++r)
                pv[mt][r] = pnAr[mrow0 + mt * 16 + quad * 4 + r];
        float cv[8];
        #pragma unroll
        for (int nt = 0; nt < 8; ++nt) cv[nt] = cn[nt * 16 + l16];
        float sum = 0.f;
        ushort* my = exch + ((w & 3) * 64 + lane) * 68;
        #pragma unroll
        for (int mt = 0; mt < 2; ++mt)
            #pragma unroll
            for (int nt = 0; nt < 8; ++nt) {
                float d0 = pv[mt][0] + cv[nt] - 2.f * acc[mt][nt][0];
                float d1 = pv[mt][1] + cv[nt] - 2.f * acc[mt][nt][1];
                float d2 = pv[mt][2] + cv[nt] - 2.f * acc[mt][nt][2];
                float d3 = pv[mt][3] + cv[nt] - 2.f * acc[mt][nt][3];
                sum += d0 + d1 + d2 + d3;
                ushort4 hv = { f2h(d0), f2h(d1), f2h(d2), f2h(d3) };
                *(ushort4*)&my[(mt * 8 + nt) * 4] = hv;
            }
        #pragma unroll
        for (int off = 32; off >= 1; off >>= 1) sum += __shfl_down(sum, off, 64);
        if (lane == 0) atomicAdd(accum, sum);
    }
    __syncthreads();
    if (mat == 0) {
        float bv[8];
        #pragma unroll
        for (int nt = 0; nt < 8; ++nt) bv[nt] = bias[nt * 16 + l16];
        const ushort* my = exch + ((w & 3) * 64 + lane) * 68;
        #pragma unroll
        for (int mt = 0; mt < 2; ++mt) {
            int gmb = n0 + mrow0 + mt * 16 + quad * 4;
            #pragma unroll
            for (int nt = 0; nt < 8; ++nt) {
                int gf = nt * 16 + l16;
                ushort4 hv = *(const ushort4*)&my[(mt * 8 + nt) * 4];
                ushort dd[4] = { hv.x, hv.y, hv.z, hv.w };
                #pragma unroll
                for (int r = 0; r < 4; ++r) {
                    uint pkv = ((uint)dd[r] << 16) | (uint)f2h(acc[mt][nt][r] + bv[nt]);
                    out[(gmb + r) * F_ + gf] = pkv;
                }
            }
        }
    }
}

// ---------------- E: in-place out = conv + exp(-gamma*d) ----------------
__global__ void k_final(uint* __restrict__ out, const float* __restrict__ accum) {
    int i = blockIdx.x * 256 + threadIdx.x;       // handles elems [8i, 8i+8)
    float g = 0.5f * (float)NF / accum[0];        // gamma = 1/(2*mean)
    uint4* p = (uint4*)out;
    uint4 u0 = p[2 * i], u1 = p[2 * i + 1];
    float4 f0, f1;
    f0.x = h2f((ushort)(u0.x & 0xffff)) + __expf(-g * h2f((ushort)(u0.x >> 16)));
    f0.y = h2f((ushort)(u0.y & 0xffff)) + __expf(-g * h2f((ushort)(u0.y >> 16)));
    f0.z = h2f((ushort)(u0.z & 0xffff)) + __expf(-g * h2f((ushort)(u0.z >> 16)));
    f0.w = h2f((ushort)(u0.w & 0xffff)) + __expf(-g * h2f((ushort)(u0.w >> 16)));
    f1.x = h2f((ushort)(u1.x & 0xffff)) + __expf(-g * h2f((ushort)(u1.x >> 16)));
    f1.y = h2f((ushort)(u1.y & 0xffff)) + __expf(-g * h2f((ushort)(u1.y >> 16)));
    f1.z = h2f((ushort)(u1.z & 0xffff)) + __expf(-g * h2f((ushort)(u1.z >> 16)));
    f1.w = h2f((ushort)(u1.w & 0xffff)) + __expf(-g * h2f((ushort)(u1.w >> 16)));
    float4* q = (float4*)out;
    q[2 * i] = f0; q[2 * i + 1] = f1;             // in-place, same bytes
}

extern "C" void kernel_launch(void* const* d_in, const int* in_sizes, int n_in,
                              void* d_out, int out_size, void* d_ws, size_t ws_size,
                              hipStream_t stream) {
    const float* in   = (const float*)d_in[0];   // [32,64,64,64]
    const float* wgt  = (const float*)d_in[1];   // [3,3,64,128]
    const float* bias = (const float*)d_in[2];   // [128]
    const float* ctrl = (const float*)d_in[3];   // [3,3,64,128]
    uint* out = (uint*)d_out;

    // ws: Btw @0 (147456 B) | Btc @147456 | cn @294912 | accum @295424
    char* ws = (char*)d_ws;
    ushort* Btw   = (ushort*)(ws + 0);
    ushort* Btc   = (ushort*)(ws + 147456);
    float*  cn    = (float*) (ws + 294912);
    float*  accum = (float*) (ws + 295424);

    k_prep  <<<289,          256, 0, stream>>>(wgt, ctrl, Btw, Btc, cn, accum);
    k_main  <<<NPIX / 128,   512, 0, stream>>>(in, Btw, Btc, bias, cn, out, accum);
    k_final <<<NF / 8 / 256, 256, 0, stream>>>(out, accum);
}